// Round 2
// baseline (17.892 us; speedup 1.0000x reference)
//
#include <hip/hip_runtime.h>

#define BATCH_N 8192
#define NQ 10
#define CD 138      // comb dim = 128 + 10
#define CPAD 140    // padded to multiple of 4 floats (16B rows)
#define RT 32       // rows per block
#define NJ 40       // 4 gates * 10 qubits

__global__ __launch_bounds__(256) void qlstm_kernel(
    const float* __restrict__ x,  const float* __restrict__ hx, const float* __restrict__ cx,
    const float* __restrict__ Wf, const float* __restrict__ bf,
    const float* __restrict__ Wi, const float* __restrict__ bi,
    const float* __restrict__ Wu, const float* __restrict__ bu,
    const float* __restrict__ Wo, const float* __restrict__ bo,
    float* __restrict__ out)
{
    __shared__ float sW[NJ][CPAD];      // 22.4 KB
    __shared__ float sComb[RT][CPAD];   // 17.9 KB
    __shared__ float sB[NJ];
    __shared__ float sTheta[RT][44];
    __shared__ float sGate[4][RT][NQ];

    const int tid = threadIdx.x;
    const int r0  = blockIdx.x * RT;

    const float* Ws[4] = {Wf, Wi, Wu, Wo};
    const float* bs[4] = {bf, bi, bu, bo};

    // ---- stage weights into LDS via float4 loads + component scatter ----
    // each gate: 1380 floats = 345 float4 (16B-aligned in global)
    #pragma unroll
    for (int g = 0; g < 4; ++g) {
        const float4* w4 = (const float4*)Ws[g];
        for (int idx4 = tid; idx4 < 345; idx4 += 256) {
            float4 v = w4[idx4];
            int f = idx4 * 4;
            int j = f / CD;
            int k = f - j * CD;
            float vv[4] = {v.x, v.y, v.z, v.w};
            #pragma unroll
            for (int c = 0; c < 4; ++c) {
                int kc = k + c, jc = j;
                if (kc >= CD) { jc++; kc -= CD; }
                sW[g * NQ + jc][kc] = vv[c];
            }
        }
    }
    if (tid < 2 * NJ) sW[tid >> 1][CD + (tid & 1)] = 0.f;   // zero pad cols 138,139
    if (tid < NJ)     sB[tid] = bs[tid / NQ][tid % NQ];

    // ---- stage comb tile: x rows (float4, coalesced) + hx cols ----
    {
        const float4* x4 = (const float4*)(x + (size_t)r0 * 128);
        #pragma unroll
        for (int it = 0; it < 4; ++it) {                 // 32 rows * 32 float4
            int idx = tid + it * 256;
            int row = idx >> 5;
            int c4  = idx & 31;
            float4 v = x4[idx];
            *(float4*)&sComb[row][c4 * 4] = v;
        }
    }
    for (int idx = tid; idx < RT * NQ; idx += 256) {
        int row = idx / NQ;
        int q   = idx - row * NQ;
        sComb[row][128 + q] = hx[(size_t)r0 * NQ + idx];
    }
    if (tid < 2 * RT) sComb[tid >> 1][CD + (tid & 1)] = 0.f; // zero pad cols 138,139

    __syncthreads();

    // ---- phase A: theta[r][j] = comb[r] . W[j] + b[j] ----
    // 128 threads: 16 row-groups (rows rg, rg+16) x 8 col-groups (5 outputs)
    if (tid < 128) {
        const int rg = tid & 15;
        const int j0 = (tid >> 4) * 5;
        float acc0[5], acc1[5];
        #pragma unroll
        for (int jj = 0; jj < 5; ++jj) { acc0[jj] = sB[j0 + jj]; acc1[jj] = acc0[jj]; }
        #pragma unroll 5
        for (int k4 = 0; k4 < CPAD / 4; ++k4) {
            float4 xv0 = *(const float4*)&sComb[rg][k4 * 4];
            float4 xv1 = *(const float4*)&sComb[rg + 16][k4 * 4];
            #pragma unroll
            for (int jj = 0; jj < 5; ++jj) {
                float4 wv = *(const float4*)&sW[j0 + jj][k4 * 4];
                acc0[jj] = fmaf(xv0.x, wv.x, acc0[jj]);
                acc0[jj] = fmaf(xv0.y, wv.y, acc0[jj]);
                acc0[jj] = fmaf(xv0.z, wv.z, acc0[jj]);
                acc0[jj] = fmaf(xv0.w, wv.w, acc0[jj]);
                acc1[jj] = fmaf(xv1.x, wv.x, acc1[jj]);
                acc1[jj] = fmaf(xv1.y, wv.y, acc1[jj]);
                acc1[jj] = fmaf(xv1.z, wv.z, acc1[jj]);
                acc1[jj] = fmaf(xv1.w, wv.w, acc1[jj]);
            }
        }
        #pragma unroll
        for (int jj = 0; jj < 5; ++jj) {
            sTheta[rg][j0 + jj]      = acc0[jj];
            sTheta[rg + 16][j0 + jj] = acc1[jj];
        }
    }
    __syncthreads();

    // ---- phase B: closed-form circuit  z_q = prod_{k<=q, k=q mod 2} cos(theta_k)
    //      then sigmoid (gates f,i,o) / tanh (gate u) ----
    if (tid < 4 * RT) {
        const int r = tid & 31;
        const int g = tid >> 5;            // 0:f 1:i 2:u 3:o
        float z[NQ];
        #pragma unroll
        for (int q = 0; q < NQ; ++q) {
            float c = cosf(sTheta[r][g * NQ + q]);
            z[q] = (q < 2) ? c : z[q - 2] * c;
        }
        #pragma unroll
        for (int q = 0; q < NQ; ++q) {
            float zz = z[q];
            float val = (g == 2) ? tanhf(zz) : 1.f / (1.f + expf(-zz));
            sGate[g][r][q] = val;
        }
    }
    __syncthreads();

    // ---- phase C: LSTM combine, coalesced loads/stores ----
    const float* fG = &sGate[0][0][0];
    const float* iG = &sGate[1][0][0];
    const float* gG = &sGate[2][0][0];
    const float* oG = &sGate[3][0][0];
    for (int idx = tid; idx < RT * NQ; idx += 256) {
        float fv  = fG[idx];
        float iv  = iG[idx];
        float gv  = gG[idx];
        float ov  = oG[idx];
        float cxv = cx[(size_t)r0 * NQ + idx];
        float cn  = fv * cxv + iv * gv;
        float hn  = ov * tanhf(cn);
        out[(size_t)r0 * NQ + idx] = hn;                               // h_new
        out[(size_t)BATCH_N * NQ + (size_t)r0 * NQ + idx] = cn;        // c_new
    }
}

extern "C" void kernel_launch(void* const* d_in, const int* in_sizes, int n_in,
                              void* d_out, int out_size, void* d_ws, size_t ws_size,
                              hipStream_t stream) {
    const float* x  = (const float*)d_in[0];
    const float* hx = (const float*)d_in[1];
    const float* cx = (const float*)d_in[2];
    const float* Wf = (const float*)d_in[3];
    const float* bf = (const float*)d_in[4];
    const float* Wi = (const float*)d_in[5];
    const float* bi = (const float*)d_in[6];
    const float* Wu = (const float*)d_in[7];
    const float* bu = (const float*)d_in[8];
    const float* Wo = (const float*)d_in[9];
    const float* bo = (const float*)d_in[10];
    float* out = (float*)d_out;

    dim3 grid(BATCH_N / RT);
    dim3 block(256);
    hipLaunchKernelGGL(qlstm_kernel, grid, block, 0, stream,
                       x, hx, cx, Wf, bf, Wi, bi, Wu, bu, Wo, bo, out);
}

// Round 4
// 17.809 us; speedup vs baseline: 1.0047x; 1.0047x over previous
//
#include <hip/hip_runtime.h>

#define BATCH_N 8192
#define NQ 10
#define CD 138      // comb dim = 128 + 10
#define CPAD 140    // padded row stride (140 mod 32 = 12 -> good bank spread)
#define RT 16       // rows per block  -> grid 512 = 2 blocks/CU
#define NJ 40       // 4 gates * 10 qubits

__global__ __launch_bounds__(256) void qlstm_kernel(
    const float* __restrict__ x,  const float* __restrict__ hx, const float* __restrict__ cx,
    const float* __restrict__ Wf, const float* __restrict__ bf,
    const float* __restrict__ Wi, const float* __restrict__ bi,
    const float* __restrict__ Wu, const float* __restrict__ bu,
    const float* __restrict__ Wo, const float* __restrict__ bo,
    float* __restrict__ out)
{
    __shared__ float sW[NJ][CPAD];      // 22.4 KB
    __shared__ float sComb[RT][CPAD];   // 8.96 KB
    __shared__ float sB[NJ];
    __shared__ float sTheta[RT][44];
    __shared__ float sGate[4][RT][NQ];

    const int tid = threadIdx.x;
    const int r0  = blockIdx.x * RT;

    const float* Ws[4] = {Wf, Wi, Wu, Wo};
    const float* bs[4] = {bf, bi, bu, bo};

    // ---- prefetch cx into a register NOW (consumed in phase C after 3 barriers) ----
    float cxreg = 0.f;
    if (tid < RT * NQ) cxreg = cx[(size_t)r0 * NQ + tid];

    // ---- stage x tile: 16 rows * 32 float4 = 512 float4, 2 per thread ----
    {
        const float4* x4 = (const float4*)(x + (size_t)r0 * 128);
        float4 va = x4[tid];
        float4 vb = x4[tid + 256];
        *(float4*)&sComb[tid >> 5][(tid & 31) * 4] = va;
        *(float4*)&sComb[(tid + 256) >> 5][(tid & 31) * 4] = vb;
    }
    if (tid < RT * NQ) sComb[tid / NQ][128 + (tid % NQ)] = hx[(size_t)r0 * NQ + tid];
    if (tid < 2 * RT)  sComb[tid >> 1][CD + (tid & 1)] = 0.f;   // zero pad cols 138,139

    // ---- stage weights into LDS via float4 loads + component scatter ----
    #pragma unroll
    for (int g = 0; g < 4; ++g) {
        const float4* w4 = (const float4*)Ws[g];
        for (int idx4 = tid; idx4 < 345; idx4 += 256) {
            float4 v = w4[idx4];
            int f = idx4 * 4;
            int j = f / CD;
            int k = f - j * CD;
            float vv[4] = {v.x, v.y, v.z, v.w};
            #pragma unroll
            for (int c = 0; c < 4; ++c) {
                int kc = k + c, jc = j;
                if (kc >= CD) { jc++; kc -= CD; }
                sW[g * NQ + jc][kc] = vv[c];
            }
        }
    }
    if (tid < 2 * NJ) sW[tid >> 1][CD + (tid & 1)] = 0.f;       // zero pad cols 138,139
    if (tid < NJ)     sB[tid] = bs[tid / NQ][tid % NQ];

    __syncthreads();

    // ---- phase A: theta[r][j] = comb[r] . W[j] + b[j] ----
    // 64 threads (1 wave): 8 row-groups (rows rg, rg+8) x 8 col-groups (5 outputs)
    if (tid < 64) {
        const int rg = tid & 7;
        const int j0 = (tid >> 3) * 5;
        float acc0[5], acc1[5];
        #pragma unroll
        for (int jj = 0; jj < 5; ++jj) { acc0[jj] = sB[j0 + jj]; acc1[jj] = acc0[jj]; }
        #pragma unroll 5
        for (int k4 = 0; k4 < CPAD / 4; ++k4) {
            float4 xv0 = *(const float4*)&sComb[rg][k4 * 4];
            float4 xv1 = *(const float4*)&sComb[rg + 8][k4 * 4];
            #pragma unroll
            for (int jj = 0; jj < 5; ++jj) {
                float4 wv = *(const float4*)&sW[j0 + jj][k4 * 4];
                acc0[jj] = fmaf(xv0.x, wv.x, acc0[jj]);
                acc0[jj] = fmaf(xv0.y, wv.y, acc0[jj]);
                acc0[jj] = fmaf(xv0.z, wv.z, acc0[jj]);
                acc0[jj] = fmaf(xv0.w, wv.w, acc0[jj]);
                acc1[jj] = fmaf(xv1.x, wv.x, acc1[jj]);
                acc1[jj] = fmaf(xv1.y, wv.y, acc1[jj]);
                acc1[jj] = fmaf(xv1.z, wv.z, acc1[jj]);
                acc1[jj] = fmaf(xv1.w, wv.w, acc1[jj]);
            }
        }
        #pragma unroll
        for (int jj = 0; jj < 5; ++jj) {
            sTheta[rg][j0 + jj]     = acc0[jj];
            sTheta[rg + 8][j0 + jj] = acc1[jj];
        }
    }
    __syncthreads();

    // ---- phase B: z_q = prod_{k<=q, k=q mod 2} cos(theta_k); sigmoid/tanh ----
    // 64 threads: 16 rows x 4 gates
    if (tid < 64) {
        const int r = tid & 15;
        const int g = tid >> 4;            // 0:f 1:i 2:u 3:o
        float z[NQ];
        #pragma unroll
        for (int q = 0; q < NQ; ++q) {
            float c = cosf(sTheta[r][g * NQ + q]);
            z[q] = (q < 2) ? c : z[q - 2] * c;
        }
        #pragma unroll
        for (int q = 0; q < NQ; ++q) {
            float zz = z[q];
            float val = (g == 2) ? tanhf(zz) : 1.f / (1.f + expf(-zz));
            sGate[g][r][q] = val;
        }
    }
    __syncthreads();

    // ---- phase C: LSTM combine, coalesced stores; cx already in register ----
    if (tid < RT * NQ) {
        const float* G = &sGate[0][0][0];
        float fv = G[tid];
        float iv = G[tid + RT * NQ];
        float gv = G[tid + 2 * RT * NQ];
        float ov = G[tid + 3 * RT * NQ];
        float cn = fv * cxreg + iv * gv;
        float hn = ov * tanhf(cn);
        out[(size_t)r0 * NQ + tid] = hn;                               // h_new
        out[(size_t)BATCH_N * NQ + (size_t)r0 * NQ + tid] = cn;        // c_new
    }
}

extern "C" void kernel_launch(void* const* d_in, const int* in_sizes, int n_in,
                              void* d_out, int out_size, void* d_ws, size_t ws_size,
                              hipStream_t stream) {
    const float* x  = (const float*)d_in[0];
    const float* hx = (const float*)d_in[1];
    const float* cx = (const float*)d_in[2];
    const float* Wf = (const float*)d_in[3];
    const float* bf = (const float*)d_in[4];
    const float* Wi = (const float*)d_in[5];
    const float* bi = (const float*)d_in[6];
    const float* Wu = (const float*)d_in[7];
    const float* bu = (const float*)d_in[8];
    const float* Wo = (const float*)d_in[9];
    const float* bo = (const float*)d_in[10];
    float* out = (float*)d_out;

    dim3 grid(BATCH_N / RT);   // 512 blocks -> 2 per CU
    dim3 block(256);
    hipLaunchKernelGGL(qlstm_kernel, grid, block, 0, stream,
                       x, hx, cx, Wf, bf, Wi, bi, Wu, bu, Wo, bo, out);
}